// Round 11
// baseline (275.202 us; speedup 1.0000x reference)
//
#include <hip/hip_runtime.h>
#include <hip/hip_bf16.h>

#define DEV __device__ __forceinline__

typedef short bf16x8 __attribute__((ext_vector_type(8)));
typedef float f32x4 __attribute__((ext_vector_type(4)));
typedef unsigned int u32;
typedef unsigned int u32x4 __attribute__((ext_vector_type(4)));

constexpr int BB = 2, SS = 2048, DD = 1024, HH = 16, DHD = 64;
constexpr int MM = BB * SS; // 4096
#define QSC 0.1803368801111f  /* 0.125 * log2(e): scores in log2 domain */

#if __has_builtin(__builtin_amdgcn_exp2f)
#define EXP2(x) __builtin_amdgcn_exp2f(x)
#else
#define EXP2(x) exp2f(x)
#endif

// round-half-up bf16; bias only at exact-half cases
DEV unsigned short f2bf(float f) {
    union { float f; unsigned int u; } v; v.f = f;
    return (unsigned short)((v.u + 0x8000u) >> 16);
}
// pack two f32 -> (bf16(b)<<16)|bf16(a) : add, add, v_perm = 3 instr
#if __has_builtin(__builtin_amdgcn_perm)
DEV u32 pk2bf(float a, float b) {
    union { float f; u32 u; } ua, ub; ua.f = a; ub.f = b;
    return __builtin_amdgcn_perm(ub.u + 0x8000u, ua.u + 0x8000u, 0x07060302u);
}
#else
DEV u32 pk2bf(float a, float b) {
    union { float f; u32 u; } ua, ub; ua.f = a; ub.f = b;
    return ((ua.u + 0x8000u) >> 16) | ((ub.u + 0x8000u) & 0xffff0000u);
}
#endif

// single-instruction RNE pack (gfx950 has no builtin; inline asm per T12)
DEV u32 cvtpk2bf(float a, float b) {
    u32 r;
    asm("v_cvt_pk_bf16_f32 %0, %1, %2" : "=v"(r) : "v"(a), "v"(b));
    return r;
}

DEV bf16x8 ld_bf16x8(const unsigned short* p) { return *(const bf16x8*)p; }

// async global->LDS, 16B per lane; lds dest = wave-uniform base + lane*16
DEV void gl16(const unsigned short* g, unsigned short* l) {
    __builtin_amdgcn_global_load_lds(
        (const __attribute__((address_space(1))) u32*)g,
        (__attribute__((address_space(3))) u32*)l, 16, 0, 0);
}

// ---- prep (fused): blocks [0,4096) = x->bf16 ; [4096,8192) = W transposes ----
__global__ void prep(const float* __restrict__ x, unsigned short* __restrict__ xb,
                     const float* __restrict__ W0, const float* __restrict__ W1,
                     const float* __restrict__ W2, const float* __restrict__ W3,
                     unsigned short* __restrict__ WtBase) {
    __shared__ float tile[32][33];
    int blk = blockIdx.x;
    if (blk < 4096) {
        int i = blk * 256 + threadIdx.x;
        float4 v = ((const float4*)x)[i];
        uint2 o;
        o.x = pk2bf(v.x, v.y);
        o.y = pk2bf(v.z, v.w);
        ((uint2*)xb)[i] = o;
        return;
    }
    blk -= 4096;                 // 4 weights x 1024 tiles
    int wsel = blk >> 10;
    const float* W = (wsel == 0) ? W0 : (wsel == 1) ? W1 : (wsel == 2) ? W2 : W3;
    unsigned short* Wt = WtBase + (size_t)wsel * DD * DD;
    int t = blk & 1023;
    int n0 = (t & 31) * 32, k0 = (t >> 5) * 32;
    int tx = threadIdx.x & 31, ty = threadIdx.x >> 5; // 32 x 8
    #pragma unroll
    for (int i = 0; i < 4; ++i)
        tile[ty + 8 * i][tx] = W[(size_t)(k0 + ty + 8 * i) * DD + n0 + tx];
    __syncthreads();
    #pragma unroll
    for (int i = 0; i < 4; ++i)
        Wt[(size_t)(n0 + ty + 8 * i) * DD + k0 + tx] = f2bf(tile[tx][ty + 8 * i]);
}

// ====================== QKV GEMM v7: z-merged 128x128, 3-buffer counted vmcnt ======================
// (R8 version, unchanged: A-frags shared across the 3 products -> 10 ds_reads / 24 MFMA.)
__global__ __launch_bounds__(512, 2) void qkv_gemm(
    const unsigned short* __restrict__ xb,
    const unsigned short* __restrict__ WtBase,
    const float* __restrict__ bq, const float* __restrict__ bk, const float* __restrict__ bv,
    unsigned short* __restrict__ Qb, unsigned short* __restrict__ Kb, unsigned short* __restrict__ Vt)
{
    __shared__ __align__(16) unsigned short AL[3][128 * 32];     // 24 KB
    __shared__ __align__(16) unsigned short BL[3][3][128 * 32];  // 72 KB

    // XCD-balanced remap (R4-proven): xcd k <- xe in [4(k&1),+4), ye in [8(k>>1),+8)
    const int gid2 = blockIdx.x + 8 * blockIdx.y;   // 0..255; xcd = gid2&7
    const int xk = gid2 & 7, o = gid2 >> 3;
    const int xe = (xk & 1) * 4 + (o & 3);
    const int ye = (xk >> 1) * 8 + (o >> 2);
    const int m0g = ye * 128;
    const int n0g = xe * 128;

    const int wave = threadIdx.x >> 6, lane = threadIdx.x & 63;
    const int quad = lane >> 4, lcol = lane & 15;
    const int wr = wave >> 2, wc = wave & 3;   // 2M x 4N wave grid; per-wave 64x32 per z

    f32x4 acc[3][4][2];
    #pragma unroll
    for (int z = 0; z < 3; ++z)
        #pragma unroll
        for (int i = 0; i < 4; ++i)
            #pragma unroll
            for (int j = 0; j < 2; ++j) acc[z][i][j] = (f32x4){0.f, 0.f, 0.f, 0.f};

    // stage one K-slice for A + all 3 B: 4 gl16 per thread (vmcnt unit = 4)
    auto stage = [&](int ks, int bf) {
        int bi = threadIdx.x;                 // segment 0..511
        int row = bi >> 2, p = (bi & 3) ^ ((row >> 1) & 3);
        gl16(xb + (size_t)(m0g + row) * DD + ks + p * 8, &AL[bf][wave * 512]);
        #pragma unroll
        for (int z = 0; z < 3; ++z)
            gl16(WtBase + (size_t)z * DD * DD + (size_t)(n0g + row) * DD + ks + p * 8,
                 &BL[bf][z][wave * 512]);
    };

    auto compute = [&](int bf) {
        bf16x8 af[4];
        #pragma unroll
        for (int mt = 0; mt < 4; ++mt) {
            int row = wr * 64 + mt * 16 + lcol;
            af[mt] = ld_bf16x8(&AL[bf][(row * 4 + (quad ^ ((row >> 1) & 3))) * 8]);
        }
        #pragma unroll
        for (int z = 0; z < 3; ++z) {
            bf16x8 bz[2];
            #pragma unroll
            for (int nt = 0; nt < 2; ++nt) {
                int row = wc * 32 + nt * 16 + lcol;
                bz[nt] = ld_bf16x8(&BL[bf][z][(row * 4 + (quad ^ ((row >> 1) & 3))) * 8]);
            }
            if (z < 2) { // transposed product: D[row=out_n][col=token]
                #pragma unroll
                for (int mt = 0; mt < 4; ++mt)
                    #pragma unroll
                    for (int nt = 0; nt < 2; ++nt)
                        acc[z][mt][nt] = __builtin_amdgcn_mfma_f32_16x16x32_bf16(bz[nt], af[mt], acc[z][mt][nt], 0, 0, 0);
            } else {
                #pragma unroll
                for (int mt = 0; mt < 4; ++mt)
                    #pragma unroll
                    for (int nt = 0; nt < 2; ++nt)
                        acc[z][mt][nt] = __builtin_amdgcn_mfma_f32_16x16x32_bf16(af[mt], bz[nt], acc[z][mt][nt], 0, 0, 0);
            }
        }
    };

    stage(0, 0);
    stage(32, 1);

    // main loop: k = 0..29, buffers (k%3); vmcnt(8) = 2 stages (8 gl16) in flight
    for (int kk = 0; kk < 30; kk += 3) {
        #pragma unroll
        for (int u = 0; u < 3; ++u) {
            int k = kk + u;
            stage((k + 2) * 32, (u + 2) % 3);
            asm volatile("s_waitcnt vmcnt(8)" ::: "memory");
            __builtin_amdgcn_s_barrier();
            __builtin_amdgcn_sched_barrier(0);
            compute(u);
            __builtin_amdgcn_s_barrier();
        }
    }
    // k = 30 (buf 0): only stage(31) in flight
    asm volatile("s_waitcnt vmcnt(4)" ::: "memory");
    __builtin_amdgcn_s_barrier();
    __builtin_amdgcn_sched_barrier(0);
    compute(0);
    __builtin_amdgcn_s_barrier();
    // k = 31 (buf 1): drain
    asm volatile("s_waitcnt vmcnt(0)" ::: "memory");
    __builtin_amdgcn_s_barrier();
    __builtin_amdgcn_sched_barrier(0);
    compute(1);

    // ---- epilogue: same store math as R5, per-wave ranges 64x32 ----
    #pragma unroll
    for (int z = 0; z < 2; ++z) {
        unsigned short* dst = (z == 0) ? Qb : Kb;
        const float sc = (z == 0) ? QSC : 1.0f;
        const float* bias = (z == 0) ? bq : bk;
        #pragma unroll
        for (int mt = 0; mt < 4; ++mt) {
            int m = m0g + wr * 64 + mt * 16 + lcol;        // token -> (b,s)
            int b_ = m >> 11, s = m & (SS - 1);
            #pragma unroll
            for (int nt = 0; nt < 2; ++nt) {
                int nbt = n0g + wc * 32 + nt * 16 + quad * 4;  // 4 consecutive out_n
                int h = nbt >> 6, dh0 = nbt & 63;
                float4 bv4 = *(const float4*)&bias[nbt];
                uint2 o2;
                o2.x = pk2bf((acc[z][mt][nt][0] + bv4.x) * sc, (acc[z][mt][nt][1] + bv4.y) * sc);
                o2.y = pk2bf((acc[z][mt][nt][2] + bv4.z) * sc, (acc[z][mt][nt][3] + bv4.w) * sc);
                *(uint2*)&dst[(((size_t)b_ * HH + h) * SS + s) * DHD + dh0] = o2;
            }
        }
    }
    #pragma unroll
    for (int mt = 0; mt < 4; ++mt) {
        int mbt = m0g + wr * 64 + mt * 16 + quad * 4;      // 4 consecutive tokens
        int b_ = mbt >> 11, s0 = mbt & (SS - 1);
        #pragma unroll
        for (int nt = 0; nt < 2; ++nt) {
            int n = n0g + wc * 32 + nt * 16 + lcol;        // out_n
            int h = n >> 6, dh = n & 63;
            float bvv = bv[n];
            uint2 o2;
            o2.x = pk2bf(acc[2][mt][nt][0] + bvv, acc[2][mt][nt][1] + bvv);
            o2.y = pk2bf(acc[2][mt][nt][2] + bvv, acc[2][mt][nt][3] + bvv);
            *(uint2*)&Vt[(((size_t)b_ * HH + h) * DHD + dh) * SS + s0] = o2;
        }
    }
}

// ====================== attention v12: K direct from L2 to registers ======================
// R10 model: v10 is DS-bound (16 ds_read_b128/wave-chunk = 192 cyc; 16 waves/CU ->
// ~87% DS busy). K per (b,h) is 256KB and L2-resident on ONE XCD (g->bh pinning),
// so K needs no LDS: the fragment is exactly K[kb+kr][quad*8..] / [32+quad*8..]
// (swizzle un-applies: (quad^sw)^sw = quad) -> two coalesced 16B global loads per
// MFMA-pair, double-buffered in registers (kA/kB, static swap per scratch rule).
// loadK(c+1) issued at chunk top; the per-chunk __syncthreads vmcnt(0) drain is
// the wait point. V staging/reads unchanged (V read 8x/block -> stays in LDS).
// DS/wave-chunk: 192 -> ~108 cyc. Chain length unchanged (QK starts from regs).
__global__ __launch_bounds__(512, 4) void attn(
    const unsigned short* __restrict__ Qb,
    const unsigned short* __restrict__ Kb,
    const unsigned short* __restrict__ Vt,
    unsigned short* __restrict__ Ob)
{
    __shared__ __align__(16) unsigned short Vld[2][64 * 64]; // dh x keys, (dh&7)-swizzled blocks

    const int g = blockIdx.y * gridDim.x + blockIdx.x;  // grid (16, 32) = 512
    const int bh = (g & 7) * 4 + ((g >> 3) & 3);        // fixed g%32 per bh -> fixed XCD
    const int qt = g >> 5;                               // 0..15
    const int b = bh >> 4, h = bh & (HH - 1);
    const unsigned short* Qbh = Qb + (size_t)bh * SS * DHD;
    const unsigned short* Kbh = Kb + (size_t)bh * SS * DHD;
    const unsigned short* Vbh = Vt + (size_t)bh * DHD * SS;

    const int wave = threadIdx.x >> 6, lane = threadIdx.x & 63;
    const int quad = lane >> 4, lcol = lane & 15;
    const int rowbase = qt * 128 + wave * 16;

    // Q B-frags (n = q-row, k = dh); 0.125*log2e folded into Q
    bf16x8 qf0 = ld_bf16x8(Qbh + (size_t)(rowbase + lcol) * DHD + quad * 8);
    bf16x8 qf1 = ld_bf16x8(Qbh + (size_t)(rowbase + lcol) * DHD + 32 + quad * 8);

    // K-row this lane needs for QK MFMA-pair (kf2, j): keys 8q+4j+r land in regs
    auto krow = [&](int kf2, int j) {
        return kf2 * 32 + ((lcol >> 2) << 3) + j * 4 + (lcol & 3);
    };

    // stage V only: 8 segments, wave w handles segment w (1 gl16/thread)
    auto stageV = [&](int c, int bf) {
        int kb = c * 64;
        int bi = wave * 64 + lane;
        int dh = bi >> 3, p = (bi & 7) ^ (dh & 7);
        gl16(Vbh + (size_t)dh * SS + kb + p * 8, &Vld[bf][wave * 512]);
    };

    // K chunk -> 8 register frags [kf2*4 + j*2 + half], 16B coalesced loads
    bf16x8 kA[8], kB[8];
    auto loadK = [&](int c, bf16x8* kd) {
        int kb = c * 64;
        #pragma unroll
        for (int kf2 = 0; kf2 < 2; ++kf2)
            #pragma unroll
            for (int j = 0; j < 2; ++j) {
                const unsigned short* kp = Kbh + (size_t)(kb + krow(kf2, j)) * DHD + quad * 8;
                kd[kf2 * 4 + j * 2]     = ld_bf16x8(kp);
                kd[kf2 * 4 + j * 2 + 1] = ld_bf16x8(kp + 32);
            }
    };

    // ---- prologue: stage V chunk 0, K chunk 0 -> regs, m0 estimate ----
    stageV(0, 0);
    loadK(0, kA);
    __syncthreads();

    float m0 = -1e30f;
    #pragma unroll
    for (int kf2 = 0; kf2 < 2; ++kf2)
        #pragma unroll
        for (int j = 0; j < 2; ++j) {
            f32x4 s = (f32x4){0.f, 0.f, 0.f, 0.f};
            s = __builtin_amdgcn_mfma_f32_16x16x32_bf16(kA[kf2 * 4 + j * 2], qf0, s, 0, 0, 0);
            s = __builtin_amdgcn_mfma_f32_16x16x32_bf16(kA[kf2 * 4 + j * 2 + 1], qf1, s, 0, 0, 0);
            #pragma unroll
            for (int r = 0; r < 4; ++r) m0 = fmaxf(m0, s[r]);
        }
    #pragma unroll
    for (int msk = 1; msk < 64; msk <<= 1) m0 = fmaxf(m0, __shfl_xor(m0, msk, 64));
    const f32x4 minit = (f32x4){-m0, -m0, -m0, -m0};

    // ---- main loop over 32 chunks of 64 keys ----
    f32x4 oacc[4];
    #pragma unroll
    for (int nt = 0; nt < 4; ++nt) oacc[nt] = (f32x4){0.f, 0.f, 0.f, 0.f};
    float ps = 0.f;

    auto chunk = [&](int c, bf16x8* kc, bf16x8* kn) {
        int bf = c & 1;
        if (c + 1 < 32) { stageV(c + 1, bf ^ 1); loadK(c + 1, kn); }

        // S^T = K.Q^T (C-init = -m0) -> exp2 -> pack into PV A-frags (registers)
        bf16x8 paf[2];
        #pragma unroll
        for (int kf2 = 0; kf2 < 2; ++kf2) {
            u32 w[4];
            #pragma unroll
            for (int j = 0; j < 2; ++j) {
                f32x4 s = minit;
                s = __builtin_amdgcn_mfma_f32_16x16x32_bf16(kc[kf2 * 4 + j * 2], qf0, s, 0, 0, 0);
                s = __builtin_amdgcn_mfma_f32_16x16x32_bf16(kc[kf2 * 4 + j * 2 + 1], qf1, s, 0, 0, 0);
                float e0 = EXP2(s[0]), e1 = EXP2(s[1]);
                float e2 = EXP2(s[2]), e3 = EXP2(s[3]);
                ps += (e0 + e1) + (e2 + e3);
                w[j * 2]     = cvtpk2bf(e0, e1);
                w[j * 2 + 1] = cvtpk2bf(e2, e3);
            }
            union { u32x4 u; bf16x8 v; } pu;
            pu.u = (u32x4){w[0], w[1], w[2], w[3]};
            paf[kf2] = pu.v;
        }

        // PV: A = P (registers), B = V (from Vld) — identical to v10 reads
        #pragma unroll
        for (int kf2 = 0; kf2 < 2; ++kf2) {
            #pragma unroll
            for (int nt = 0; nt < 4; ++nt) {
                int dh = nt * 16 + lcol;
                bf16x8 vb = ld_bf16x8(&Vld[bf][(dh * 8 + ((kf2 * 4 + quad) ^ (dh & 7))) * 8]);
                oacc[nt] = __builtin_amdgcn_mfma_f32_16x16x32_bf16(paf[kf2], vb, oacc[nt], 0, 0, 0);
            }
        }
        __syncthreads();
    };

    for (int c = 0; c < 32; c += 2) {
        chunk(c, kA, kB);
        chunk(c + 1, kB, kA);
    }

    // ---- epilogue: per-row normalize (rows owned entirely by this wave) ----
    ps += __shfl_xor(ps, 16, 64);
    ps += __shfl_xor(ps, 32, 64);
    float inv = 1.0f / ps;   // valid at lanes where lcol == q-row
    #pragma unroll
    for (int r = 0; r < 4; ++r) {
        float iv = __shfl(inv, quad * 4 + r, 64);
        int srow = rowbase + quad * 4 + r;
        size_t base = (((size_t)b * SS + srow) * HH + h) * DHD;
        #pragma unroll
        for (int nt = 0; nt < 4; ++nt)
            Ob[base + nt * 16 + lcol] = f2bf(oacc[nt][r] * iv);
    }
}

// ====================== output GEMM v3: 3-buffer counted vmcnt, BK=32 ======================
// (R9 version, unchanged.)
__global__ __launch_bounds__(256, 4) void out_gemm(
    const unsigned short* __restrict__ Ob,
    const unsigned short* __restrict__ Wto,
    const float* __restrict__ bo,
    float* __restrict__ out)
{
    __shared__ __align__(16) unsigned short Wld[3][128 * 32]; // out_n x k, 24 KB
    __shared__ __align__(16) unsigned short Old[3][64 * 32];  // token x k, 12 KB

    // XCD-balanced remap: 512 blocks; xcd k <- xe in {4(k&1)..}, ye in {16(k>>1)..}
    const int gid2 = blockIdx.x + 8 * blockIdx.y;   // 0..511; xcd = gid2&7
    const int xk = gid2 & 7, o = gid2 >> 3;         // o: 0..63
    const int xe = (xk & 1) * 4 + (o & 3);          // 0..7   (n-tile)
    const int ye = (xk >> 1) * 16 + (o >> 2);       // 0..63  (m-tile)
    const int m0g = ye * 64;    // tokens
    const int n0g = xe * 128;   // out_n

    const int wave = threadIdx.x >> 6, lane = threadIdx.x & 63;
    const int quad = lane >> 4, lcol = lane & 15;
    const int nb = wave * 32;           // wave's out_n sub-range

    f32x4 acc[2][4];
    #pragma unroll
    for (int i = 0; i < 2; ++i)
        #pragma unroll
        for (int j = 0; j < 4; ++j) acc[i][j] = (f32x4){0.f, 0.f, 0.f, 0.f};

    // stage one 32-wide K-slice: W 128 rows (2 gl16) + O 64 rows (1 gl16) = 3/thread
    auto stage = [&](int ks, int bf) {
        #pragma unroll
        for (int i = 0; i < 2; ++i) {
            int bi = i * 256 + threadIdx.x;
            int r = bi >> 2, p = (bi & 3) ^ ((r >> 1) & 3);
            gl16(Wto + (size_t)(n0g + r) * DD + ks + p * 8, &Wld[bf][(i * 4 + wave) * 512]);
        }
        {
            int bi = threadIdx.x;
            int r = bi >> 2, p = (bi & 3) ^ ((r >> 1) & 3);
            gl16(Ob + (size_t)(m0g + r) * DD + ks + p * 8, &Old[bf][wave * 512]);
        }
    };

    auto compute = [&](int bf) {
        bf16x8 wf[2], of[4];
        #pragma unroll
        for (int i = 0; i < 2; ++i) {
            int row = nb + i * 16 + lcol;
            wf[i] = ld_bf16x8(&Wld[bf][(row * 4 + (quad ^ ((row >> 1) & 3))) * 8]);
        }
        #pragma unroll
        for (int j = 0; j < 4; ++j) {
            int row = j * 16 + lcol;
            of[j] = ld_bf16x8(&Old[bf][(row * 4 + (quad ^ ((row >> 1) & 3))) * 8]);
        }
        #pragma unroll
        for (int i = 0; i < 2; ++i)
            #pragma unroll
            for (int j = 0; j < 4; ++j)
                acc[i][j] = __builtin_amdgcn_mfma_f32_16x16x32_bf16(wf[i], of[j], acc[i][j], 0, 0, 0);
    };

    stage(0, 0);
    stage(32, 1);

    // main loop: k = 0..29, buffers (k%3); vmcnt(6) = 2 stages (6 gl16) in flight
    for (int kk = 0; kk < 30; kk += 3) {
        #pragma unroll
        for (int u = 0; u < 3; ++u) {
            int k = kk + u;
            stage((k + 2) * 32, (u + 2) % 3);
            asm volatile("s_waitcnt vmcnt(6)" ::: "memory");
            __builtin_amdgcn_s_barrier();
            __builtin_amdgcn_sched_barrier(0);
            compute(u);
            __builtin_amdgcn_s_barrier();
        }
    }
    // k = 30 (buf 0): only stage(31) in flight
    asm volatile("s_waitcnt vmcnt(3)" ::: "memory");
    __builtin_amdgcn_s_barrier();
    __builtin_amdgcn_sched_barrier(0);
    compute(0);
    __builtin_amdgcn_s_barrier();
    // k = 31 (buf 1): drain
    asm volatile("s_waitcnt vmcnt(0)" ::: "memory");
    __builtin_amdgcn_s_barrier();
    __builtin_amdgcn_sched_barrier(0);
    compute(1);

    // C: col = token (lcol within j-tile), row = out_n (quad*4 + r, consecutive)
    #pragma unroll
    for (int i = 0; i < 2; ++i) {
        int n4 = n0g + nb + i * 16 + quad * 4;
        float4 bv4 = *(const float4*)&bo[n4];
        #pragma unroll
        for (int j = 0; j < 4; ++j) {
            int token = m0g + j * 16 + lcol;
            float4 o2;
            o2.x = acc[i][j][0] + bv4.x;
            o2.y = acc[i][j][1] + bv4.y;
            o2.z = acc[i][j][2] + bv4.z;
            o2.w = acc[i][j][3] + bv4.w;
            *(float4*)&out[(size_t)token * DD + n4] = o2;
        }
    }
}

extern "C" void kernel_launch(void* const* d_in, const int* in_sizes, int n_in,
                              void* d_out, int out_size, void* d_ws, size_t ws_size,
                              hipStream_t stream)
{
    const float* x  = (const float*)d_in[0];
    const float* Wq = (const float*)d_in[1];
    const float* bq = (const float*)d_in[2];
    const float* Wk = (const float*)d_in[3];
    const float* bk = (const float*)d_in[4];
    const float* Wv = (const float*)d_in[5];
    const float* bv = (const float*)d_in[6];
    const float* Wo = (const float*)d_in[7];
    const float* bo = (const float*)d_in[8];
    float* out = (float*)d_out;

    unsigned short* ws = (unsigned short*)d_ws;
    unsigned short* Wt  = ws;                        // 4 * D*D (q,k,v,o)
    unsigned short* Wto = Wt + 3 * (size_t)DD * DD;
    unsigned short* Qb  = Wt + 4 * (size_t)DD * DD;  // M*D each
    unsigned short* Kb  = Qb + (size_t)MM * DD;
    unsigned short* Vt  = Kb + (size_t)MM * DD;
    unsigned short* xb  = Vt + (size_t)MM * DD;      // total 40 MB
    unsigned short* Ob  = xb;                        // alias: xb dead after qkv_gemm

    prep<<<8192, 256, 0, stream>>>(x, xb, Wq, Wk, Wv, Wo, Wt);

    qkv_gemm<<<dim3(8, 32), 512, 0, stream>>>(xb, Wt, bq, bk, bv, Qb, Kb, Vt);

    attn<<<dim3(16, 32), 512, 0, stream>>>(Qb, Kb, Vt, Ob);

    out_gemm<<<dim3(8, 64), 256, 0, stream>>>(Ob, Wto, bo, out);
}